// Round 3
// baseline (385.662 us; speedup 1.0000x reference)
//
#include <hip/hip_runtime.h>
#include <hip/hip_bf16.h>

// Problem constants (B=4, S=2048, D=1024, E=8, F=4096)
#define TOKENS   8192
#define DDIM     1024
#define NEXP     8
#define FDIM     4096
#define CAPACITY 1280
#define NYT      5          // CAPACITY / 256 M-tiles

typedef __attribute__((ext_vector_type(8))) __bf16 bf16x8;
typedef __attribute__((ext_vector_type(4))) __bf16 bf16x4;
typedef __attribute__((ext_vector_type(4))) float  f32x4;

typedef __attribute__((address_space(1))) const void gvoid_t;
typedef __attribute__((address_space(3))) void       lvoid_t;

__device__ __forceinline__ void async16(const void* g, void* l) {
  // 16B per lane, LDS dest = wave-uniform base + lane*16 (HW behavior)
  __builtin_amdgcn_global_load_lds((gvoid_t*)g, (lvoid_t*)l, 16, 0, 0);
}

// ---------------- gating: logits, softmax, top-1 (all f32, must match ref routing) --------
__global__ void gate_kernel(const float* __restrict__ x, const float* __restrict__ gw,
                            int* __restrict__ eidx, float* __restrict__ prob) {
  const int t = blockIdx.x;
  const int lane = threadIdx.x;           // 64 threads
  const float* xp = x + (size_t)t * DDIM;
  float acc[NEXP];
#pragma unroll
  for (int e = 0; e < NEXP; ++e) acc[e] = 0.f;
#pragma unroll 4
  for (int i = 0; i < DDIM / 64; ++i) {
    const int d = i * 64 + lane;
    const float xv = xp[d];
    const f32x4 g0 = *(const f32x4*)(gw + d * NEXP);
    const f32x4 g1 = *(const f32x4*)(gw + d * NEXP + 4);
    acc[0] += xv * g0[0]; acc[1] += xv * g0[1];
    acc[2] += xv * g0[2]; acc[3] += xv * g0[3];
    acc[4] += xv * g1[0]; acc[5] += xv * g1[1];
    acc[6] += xv * g1[2]; acc[7] += xv * g1[3];
  }
#pragma unroll
  for (int e = 0; e < NEXP; ++e) {
    float v = acc[e];
#pragma unroll
    for (int off = 32; off; off >>= 1) v += __shfl_xor(v, off);
    acc[e] = v;
  }
  if (lane == 0) {
    float m = acc[0]; int mi = 0;
#pragma unroll
    for (int e = 1; e < NEXP; ++e) if (acc[e] > m) { m = acc[e]; mi = e; }  // first-occurrence argmax
    float s = 0.f;
#pragma unroll
    for (int e = 0; e < NEXP; ++e) s += __expf(acc[e] - m);
    eidx[t] = mi;
    prob[t] = 1.f / s;       // softmax prob of the argmax expert
  }
}

// ---------------- deterministic per-expert cumsum positions + slot->token map + counts ----
__global__ void scan_kernel(const int* __restrict__ eidx, int* __restrict__ src,
                            int* __restrict__ counts) {
  __shared__ int buf[2][NEXP][256];
  const int tid = threadIdx.x;            // 256 threads, 1 block
  for (int i = tid; i < NEXP * CAPACITY; i += 256) src[i] = -1;
  const int t0 = tid * (TOKENS / 256);    // 32 tokens per thread
#pragma unroll
  for (int e = 0; e < NEXP; ++e) buf[0][e][tid] = 0;
  for (int k = 0; k < TOKENS / 256; ++k) {
    const int e = eidx[t0 + k];
    buf[0][e][tid]++;                     // LDS histogram
  }
  __syncthreads();
  int cur = 0;
  for (int off = 1; off < 256; off <<= 1) {   // Hillis-Steele inclusive scan over threads
#pragma unroll
    for (int e = 0; e < NEXP; ++e) {
      int v = buf[cur][e][tid];
      if (tid >= off) v += buf[cur][e][tid - off];
      buf[cur ^ 1][e][tid] = v;
    }
    __syncthreads();
    cur ^= 1;
  }
  if (tid < NEXP) counts[tid] = buf[cur][tid][255];   // per-expert totals (for M-tile skip)
  // exclusive base -> running counters in the other buffer (own slot only, no race)
#pragma unroll
  for (int e = 0; e < NEXP; ++e)
    buf[cur ^ 1][e][tid] = (tid > 0) ? buf[cur][e][tid - 1] : 0;
  for (int k = 0; k < TOKENS / 256; ++k) {
    const int t = t0 + k;
    const int e = eidx[t];
    const int p = buf[cur ^ 1][e][tid]++;
    if (p < CAPACITY) src[e * CAPACITY + p] = t;   // p>=CAP => token dropped
  }
}

// ---------------- dispatch: scatter tokens (f32 -> bf16) into [E*CAP, D]; zero empty slots
__global__ void dispatch_kernel(const float* __restrict__ tokens, const int* __restrict__ src,
                                __bf16* __restrict__ Xb) {
  const int slot = blockIdx.x;            // E*CAP blocks
  const int tid  = threadIdx.x;           // 256 threads, 4 elems each
  const int t = src[slot];
  bf16x4* dst = (bf16x4*)(Xb + (size_t)slot * DDIM);
  bf16x4 o;
  if (t >= 0) {
    const f32x4 v = ((const f32x4*)(tokens + (size_t)t * DDIM))[tid];
    o[0] = (__bf16)v[0]; o[1] = (__bf16)v[1]; o[2] = (__bf16)v[2]; o[3] = (__bf16)v[3];
  } else {
    o[0] = (__bf16)0.f; o[1] = (__bf16)0.f; o[2] = (__bf16)0.f; o[3] = (__bf16)0.f;
  }
  dst[tid] = o;
}

// ---------------- weight convert f32->bf16 with transpose: w[e][R][C] -> wt[e][C][R] ------
__global__ void transpose_convert_kernel(const float* __restrict__ w, __bf16* __restrict__ wt,
                                         int R, int C) {
  __shared__ __bf16 tile[64][65];         // +1 pad: conflict-free transpose
  const int e = blockIdx.z;
  const float* wp = w + (size_t)e * R * C;
  __bf16* op = wt + (size_t)e * R * C;
  const int c0 = blockIdx.x * 64, r0 = blockIdx.y * 64;
  const int tx = threadIdx.x, ty = threadIdx.y;   // (64,4)
#pragma unroll
  for (int i = 0; i < 16; ++i) {
    const int r = ty + i * 4;
    tile[r][tx] = (__bf16)wp[(size_t)(r0 + r) * C + c0 + tx];
  }
  __syncthreads();
#pragma unroll
  for (int i = 0; i < 16; ++i) {
    const int cc = ty + i * 4;
    op[(size_t)(c0 + cc) * R + r0 + tx] = tile[tx][cc];
  }
}

// ---------------- grouped GEMM, 256xBN tile, BK=64, 8 waves, T3+T4 pipelined --------------
// C[e] = A[e][M=CAP,K] @ B[e][N,K]^T.  MODE 0: relu->bf16 into Cbf (N=FDIM, BN=256).
// MODE 1: scatter f32 out[t] = prob[t]*val via src (N=DDIM, BN=128).
// Schedule per K-tile t (buf c=t&1): 2 MFMA phases (kk=0,1) reading buf c ->
// barrier (buf c dead) -> issue STAGE(buf c <- tile t+2) -> s_waitcnt vmcnt(TOT)
// (tile t+1 landed; t+2's TOT loads stay in flight across the barrier) -> barrier.
// vmcnt never drains to 0 in steady state (T4); LDS XOR-swizzled via pre-swizzled
// global source + swizzled ds_read (0 conflicts, verified round 1).
template <int BN, int MODE>
__global__ __launch_bounds__(512, 2)
void gemm8_kernel(const __bf16* __restrict__ A, const __bf16* __restrict__ B,
                  __bf16* __restrict__ Cbf, float* __restrict__ out,
                  const int* __restrict__ src, const float* __restrict__ prob,
                  const int* __restrict__ counts,
                  int K, size_t sA, size_t sB, size_t sC) {
  constexpr int N   = (MODE == 0) ? FDIM : DDIM;
  constexpr int NX  = N / BN;
  constexpr int HB  = BN / 128;        // B half-tiles per K-tile
  constexpr int NF  = BN / 64;         // n-fragments per wave
  constexpr int WNC = 16 * NF;         // cols per wave
  __shared__ char lds[64 * 1024 + BN * 256];   // A: 2buf x 2half x 16KB; B: 2buf x HB x 16KB
  char* ldsA = lds;
  char* ldsB = lds + 64 * 1024;

  // bijective XCD swizzle (nwg % 8 == 0 for both instantiations)
  const int nwg = NX * NYT * NEXP;
  int wg = blockIdx.x;
  wg = (wg & 7) * (nwg >> 3) + (wg >> 3);
  const int e   = wg / (NX * NYT);
  const int rem = wg - e * (NX * NYT);
  const int ty  = rem % NYT;           // y fastest: consecutive ids share B-panel (L2)
  const int tx  = rem / NYT;
  const int m0  = ty * 256, n0 = tx * BN;

  // M-tile skip: output rows >= count[e] are never combined (src<0), so skip whole tiles
  const int cnt   = counts[e];
  const int tiles = (cnt + 255) >> 8;
  if (ty >= ((tiles < NYT) ? tiles : NYT)) return;

  const __bf16* Ae = A + (size_t)e * sA;
  const __bf16* Be = B + (size_t)e * sB;
  const int tid = threadIdx.x;
  const int wid = tid >> 6, lane = tid & 63;
  const int wm = wid >> 2, wn = wid & 3;     // 2M x 4N wave grid, per-wave out 128 x WNC
  const int rl = lane & 15, gl = lane >> 4;

  f32x4 acc[8][NF];
#pragma unroll
  for (int m = 0; m < 8; ++m)
#pragma unroll
    for (int n = 0; n < NF; ++n) acc[m][n] = (f32x4){0.f, 0.f, 0.f, 0.f};

  auto stage = [&](int c, int kt) {     // issue TOT = 4 + 2*HB async16 per thread
    const int k0 = kt * 64;
#pragma unroll
    for (int h = 0; h < 2; ++h)
#pragma unroll
      for (int i = 0; i < 2; ++i) {
        const int s = i * 512 + tid, row = s >> 3, cg = (s & 7) ^ (row & 7);
        async16(Ae + (size_t)(m0 + h * 128 + row) * K + k0 + cg * 8,
                ldsA + (c * 2 + h) * 16384 + s * 16);
      }
#pragma unroll
    for (int h = 0; h < HB; ++h)
#pragma unroll
      for (int i = 0; i < 2; ++i) {
        const int s = i * 512 + tid, row = s >> 3, cg = (s & 7) ^ (row & 7);
        async16(Be + (size_t)(n0 + h * 128 + row) * K + k0 + cg * 8,
                ldsB + (c * HB + h) * 16384 + s * 16);
      }
  };

  auto phase = [&](int c, int kk) {     // 8+NF ds_read_b128 -> 8*NF MFMA
    bf16x8 af[8], bv[NF];
#pragma unroll
    for (int m = 0; m < 8; ++m) {
      const int rowin = m * 16 + rl;
      af[m] = *(const bf16x8*)(ldsA + (c * 2 + wm) * 16384 + rowin * 128 +
                               (((kk * 4 + gl) ^ (rowin & 7)) * 16));
    }
#pragma unroll
    for (int n = 0; n < NF; ++n) {
      const int rowB = wn * WNC + n * 16 + rl;
      const int h = rowB >> 7, rowin = rowB & 127;
      bv[n] = *(const bf16x8*)(ldsB + (c * HB + h) * 16384 + rowin * 128 +
                               (((kk * 4 + gl) ^ (rowin & 7)) * 16));
    }
    __builtin_amdgcn_s_setprio(1);
#pragma unroll
    for (int m = 0; m < 8; ++m)
#pragma unroll
      for (int n = 0; n < NF; ++n)
        acc[m][n] = __builtin_amdgcn_mfma_f32_16x16x32_bf16(af[m], bv[n], acc[m][n], 0, 0, 0);
    __builtin_amdgcn_s_setprio(0);
  };

#define WAIT_TOT() do { if constexpr (HB == 2) \
      asm volatile("s_waitcnt vmcnt(8)" ::: "memory"); \
    else asm volatile("s_waitcnt vmcnt(6)" ::: "memory"); } while (0)

  const int nkt = K >> 6;               // 16 (GEMM1) / 64 (GEMM2) K-tiles, always >= 2
  stage(0, 0);
  stage(1, 1);
  WAIT_TOT();                           // tile 0 landed; tile 1 stays in flight
  asm volatile("" ::: "memory");
  __builtin_amdgcn_s_barrier();
  asm volatile("" ::: "memory");

  for (int t = 0; t < nkt; ++t) {
    const int c = t & 1;
    phase(c, 0);
    phase(c, 1);
    if (t + 1 < nkt) {
      asm volatile("" ::: "memory");
      __builtin_amdgcn_s_barrier();     // B1: all waves done reading buf c
      asm volatile("" ::: "memory");
      if (t + 2 < nkt) {
        stage(c, t + 2);                // overwrite dead buf c with tile t+2
        WAIT_TOT();                     // tile t+1 retired in every wave (t+2 in flight)
      } else {
        asm volatile("s_waitcnt vmcnt(0)" ::: "memory");
      }
      asm volatile("" ::: "memory");
      __builtin_amdgcn_s_barrier();     // B2: buf c^1 (tile t+1) visible to all
      asm volatile("" ::: "memory");
    }
  }
#undef WAIT_TOT

  // C/D layout: col = lane&15, row = (lane>>4)*4 + reg  [m89/m91 verified]
  if (MODE == 0) {
    __bf16* Ce = Cbf + (size_t)e * sC;
#pragma unroll
    for (int m = 0; m < 8; ++m)
#pragma unroll
      for (int j = 0; j < 4; ++j) {
        const int row = m0 + wm * 128 + m * 16 + gl * 4 + j;
#pragma unroll
        for (int n = 0; n < NF; ++n) {
          const int col = n0 + wn * WNC + n * 16 + rl;
          float v = acc[m][n][j];
          v = v > 0.f ? v : 0.f;        // fused ReLU
          Ce[(size_t)row * N + col] = (__bf16)v;
        }
      }
  } else {
#pragma unroll
    for (int m = 0; m < 8; ++m)
#pragma unroll
      for (int j = 0; j < 4; ++j) {
        const int slot = m0 + wm * 128 + m * 16 + gl * 4 + j;
        const int t = src[e * CAPACITY + slot];
        if (t >= 0) {
          const float p = prob[t];
          float* op = out + (size_t)t * N;
#pragma unroll
          for (int n = 0; n < NF; ++n) {
            const int col = n0 + wn * WNC + n * 16 + rl;
            op[col] = p * acc[m][n][j]; // fused combine (scale + scatter)
          }
        }
      }
  }
}

extern "C" void kernel_launch(void* const* d_in, const int* in_sizes, int n_in,
                              void* d_out, int out_size, void* d_ws, size_t ws_size,
                              hipStream_t stream) {
  const float* x  = (const float*)d_in[0];
  const float* gw = (const float*)d_in[1];
  const float* w1 = (const float*)d_in[2];
  const float* w2 = (const float*)d_in[3];
  float* out = (float*)d_out;

  char* ws = (char*)d_ws;
  size_t off = 0;
  auto alloc = [&](size_t bytes) {
    void* p = ws + off;
    off += (bytes + 255) & ~(size_t)255;
    return p;
  };
  __bf16* W1bT = (__bf16*)alloc((size_t)NEXP * FDIM * DDIM * 2);   // [E][F][D] bf16
  __bf16* W2bT = (__bf16*)alloc((size_t)NEXP * DDIM * FDIM * 2);   // [E][D][F] bf16
  __bf16* Xb   = (__bf16*)alloc((size_t)NEXP * CAPACITY * DDIM * 2);
  __bf16* Hb   = (__bf16*)alloc((size_t)NEXP * CAPACITY * FDIM * 2);
  int*   eidx  = (int*)alloc(TOKENS * sizeof(int));
  float* prob  = (float*)alloc(TOKENS * sizeof(float));
  int*   srcm  = (int*)alloc(NEXP * CAPACITY * sizeof(int));
  int*   cnts  = (int*)alloc(NEXP * sizeof(int));
  (void)ws_size; (void)in_sizes; (void)n_in;

  hipMemsetAsync(d_out, 0, (size_t)out_size * sizeof(float), stream);  // dropped tokens -> 0

  gate_kernel<<<TOKENS, 64, 0, stream>>>(x, gw, eidx, prob);
  scan_kernel<<<1, 256, 0, stream>>>(eidx, srcm, cnts);
  dispatch_kernel<<<NEXP * CAPACITY, 256, 0, stream>>>(x, srcm, Xb);
  transpose_convert_kernel<<<dim3(FDIM / 64, DDIM / 64, NEXP), dim3(64, 4), 0, stream>>>(
      w1, W1bT, DDIM, FDIM);
  transpose_convert_kernel<<<dim3(DDIM / 64, FDIM / 64, NEXP), dim3(64, 4), 0, stream>>>(
      w2, W2bT, FDIM, DDIM);
  // H = relu(Xb @ W1^T): 256x256 tiles, grid = 16*5*8
  gemm8_kernel<256, 0><<<(FDIM / 256) * NYT * NEXP, 512, 0, stream>>>(
      Xb, W1bT, Hb, nullptr, nullptr, nullptr, cnts,
      DDIM, (size_t)CAPACITY * DDIM, (size_t)FDIM * DDIM, (size_t)CAPACITY * FDIM);
  // out[t] = prob[t] * (H @ W2^T)[slot]: 256x128 tiles, grid = 8*5*8
  gemm8_kernel<128, 1><<<(DDIM / 128) * NYT * NEXP, 512, 0, stream>>>(
      Hb, W2bT, nullptr, out, srcm, prob, cnts,
      FDIM, (size_t)CAPACITY * FDIM, (size_t)DDIM * FDIM, 0);
}

// Round 4
// 380.091 us; speedup vs baseline: 1.0147x; 1.0147x over previous
//
#include <hip/hip_runtime.h>
#include <hip/hip_bf16.h>

// Problem constants (B=4, S=2048, D=1024, E=8, F=4096)
#define TOKENS   8192
#define DDIM     1024
#define NEXP     8
#define FDIM     4096
#define CAPACITY 1280
#define NYT      5          // CAPACITY / 256 M-tiles

typedef __attribute__((ext_vector_type(8))) __bf16 bf16x8;
typedef __attribute__((ext_vector_type(4))) __bf16 bf16x4;
typedef __attribute__((ext_vector_type(4))) float  f32x4;

typedef __attribute__((address_space(1))) const void gvoid_t;
typedef __attribute__((address_space(3))) void       lvoid_t;

__device__ __forceinline__ void async16(const void* g, void* l) {
  // 16B per lane; LDS dest MUST be wave-uniform (HW adds lane*16). Divergent
  // LDS operands get waterfalled by the compiler (round-2's 20x regression).
  __builtin_amdgcn_global_load_lds((gvoid_t*)g, (lvoid_t*)l, 16, 0, 0);
}

// ---------------- gating: logits, softmax, top-1 (all f32, must match ref routing) --------
__global__ void gate_kernel(const float* __restrict__ x, const float* __restrict__ gw,
                            int* __restrict__ eidx, float* __restrict__ prob) {
  const int t = blockIdx.x;
  const int lane = threadIdx.x;           // 64 threads
  const float* xp = x + (size_t)t * DDIM;
  float acc[NEXP];
#pragma unroll
  for (int e = 0; e < NEXP; ++e) acc[e] = 0.f;
#pragma unroll 4
  for (int i = 0; i < DDIM / 64; ++i) {
    const int d = i * 64 + lane;
    const float xv = xp[d];
    const f32x4 g0 = *(const f32x4*)(gw + d * NEXP);
    const f32x4 g1 = *(const f32x4*)(gw + d * NEXP + 4);
    acc[0] += xv * g0[0]; acc[1] += xv * g0[1];
    acc[2] += xv * g0[2]; acc[3] += xv * g0[3];
    acc[4] += xv * g1[0]; acc[5] += xv * g1[1];
    acc[6] += xv * g1[2]; acc[7] += xv * g1[3];
  }
#pragma unroll
  for (int e = 0; e < NEXP; ++e) {
    float v = acc[e];
#pragma unroll
    for (int off = 32; off; off >>= 1) v += __shfl_xor(v, off);
    acc[e] = v;
  }
  if (lane == 0) {
    float m = acc[0]; int mi = 0;
#pragma unroll
    for (int e = 1; e < NEXP; ++e) if (acc[e] > m) { m = acc[e]; mi = e; }  // first-occurrence argmax
    float s = 0.f;
#pragma unroll
    for (int e = 0; e < NEXP; ++e) s += __expf(acc[e] - m);
    eidx[t] = mi;
    prob[t] = 1.f / s;       // softmax prob of the argmax expert
  }
}

// ---------------- deterministic per-expert cumsum positions + slot->token map + counts ----
__global__ void scan_kernel(const int* __restrict__ eidx, int* __restrict__ src,
                            int* __restrict__ counts) {
  __shared__ int buf[2][NEXP][256];
  const int tid = threadIdx.x;            // 256 threads, 1 block
  for (int i = tid; i < NEXP * CAPACITY; i += 256) src[i] = -1;
  const int t0 = tid * (TOKENS / 256);    // 32 tokens per thread
#pragma unroll
  for (int e = 0; e < NEXP; ++e) buf[0][e][tid] = 0;
  for (int k = 0; k < TOKENS / 256; ++k) {
    const int e = eidx[t0 + k];
    buf[0][e][tid]++;                     // LDS histogram
  }
  __syncthreads();
  int cur = 0;
  for (int off = 1; off < 256; off <<= 1) {   // Hillis-Steele inclusive scan over threads
#pragma unroll
    for (int e = 0; e < NEXP; ++e) {
      int v = buf[cur][e][tid];
      if (tid >= off) v += buf[cur][e][tid - off];
      buf[cur ^ 1][e][tid] = v;
    }
    __syncthreads();
    cur ^= 1;
  }
  if (tid < NEXP) counts[tid] = buf[cur][tid][255];   // per-expert totals (for M-tile skip)
  // exclusive base -> running counters in the other buffer (own slot only, no race)
#pragma unroll
  for (int e = 0; e < NEXP; ++e)
    buf[cur ^ 1][e][tid] = (tid > 0) ? buf[cur][e][tid - 1] : 0;
  for (int k = 0; k < TOKENS / 256; ++k) {
    const int t = t0 + k;
    const int e = eidx[t];
    const int p = buf[cur ^ 1][e][tid]++;
    if (p < CAPACITY) src[e * CAPACITY + p] = t;   // p>=CAP => token dropped
  }
}

// ---------------- dispatch: scatter tokens (f32 -> bf16) into [E*CAP, D]; zero empty slots
__global__ void dispatch_kernel(const float* __restrict__ tokens, const int* __restrict__ src,
                                __bf16* __restrict__ Xb) {
  const int slot = blockIdx.x;            // E*CAP blocks
  const int tid  = threadIdx.x;           // 256 threads, 4 elems each
  const int t = src[slot];
  bf16x4* dst = (bf16x4*)(Xb + (size_t)slot * DDIM);
  bf16x4 o;
  if (t >= 0) {
    const f32x4 v = ((const f32x4*)(tokens + (size_t)t * DDIM))[tid];
    o[0] = (__bf16)v[0]; o[1] = (__bf16)v[1]; o[2] = (__bf16)v[2]; o[3] = (__bf16)v[3];
  } else {
    o[0] = (__bf16)0.f; o[1] = (__bf16)0.f; o[2] = (__bf16)0.f; o[3] = (__bf16)0.f;
  }
  dst[tid] = o;
}

// ---------------- weight convert f32->bf16 with transpose: w[e][R][C] -> wt[e][C][R] ------
__global__ void transpose_convert_kernel(const float* __restrict__ w, __bf16* __restrict__ wt,
                                         int R, int C) {
  __shared__ __bf16 tile[64][65];         // +1 pad: conflict-free transpose
  const int e = blockIdx.z;
  const float* wp = w + (size_t)e * R * C;
  __bf16* op = wt + (size_t)e * R * C;
  const int c0 = blockIdx.x * 64, r0 = blockIdx.y * 64;
  const int tx = threadIdx.x, ty = threadIdx.y;   // (64,4)
#pragma unroll
  for (int i = 0; i < 16; ++i) {
    const int r = ty + i * 4;
    tile[r][tx] = (__bf16)wp[(size_t)(r0 + r) * C + c0 + tx];
  }
  __syncthreads();
#pragma unroll
  for (int i = 0; i < 16; ++i) {
    const int cc = ty + i * 4;
    op[(size_t)(c0 + cc) * R + r0 + tx] = tile[tx][cc];
  }
}

// ---------------- grouped GEMM, 256xBN tile, BK=64, 8 waves, counted-vmcnt pipeline -------
// C[e] = A[e][M=CAP,K] @ B[e][N,K]^T.  MODE 0: relu->bf16 into Cbf (N=FDIM, BN=256).
// MODE 1: scatter f32 out[t] = prob[t]*val via src (N=DDIM, BN=128).
// Per K-tile t (buf c=t&1): 2 MFMA phases reading buf c -> B1 (buf c dead) ->
// stage(buf c <- tile t+2) -> s_waitcnt vmcnt(TOT) (tile t+1 landed; t+2 stays
// in flight across the barrier, T4) -> B2. LDS XOR-swizzled via pre-swizzled
// global SOURCE + swizzled ds_read; LDS dest stays linear & wave-uniform.
template <int BN, int MODE>
__global__ __launch_bounds__(512, 2)
void gemm8_kernel(const __bf16* __restrict__ A, const __bf16* __restrict__ B,
                  __bf16* __restrict__ Cbf, float* __restrict__ out,
                  const int* __restrict__ src, const float* __restrict__ prob,
                  const int* __restrict__ counts,
                  int K, size_t sA, size_t sB, size_t sC) {
  constexpr int N   = (MODE == 0) ? FDIM : DDIM;
  constexpr int NX  = N / BN;
  constexpr int HB  = BN / 128;        // B half-tiles per K-tile
  constexpr int NF  = BN / 64;         // n-fragments per wave
  constexpr int WNC = 16 * NF;         // cols per wave
  __shared__ char lds[64 * 1024 + BN * 256];   // A: 2buf x 2half x 16KB; B: 2buf x HB x 16KB
  char* ldsA = lds;
  char* ldsB = lds + 64 * 1024;

  // bijective XCD swizzle (nwg % 8 == 0 for both instantiations)
  const int nwg = NX * NYT * NEXP;
  int wg = blockIdx.x;
  wg = (wg & 7) * (nwg >> 3) + (wg >> 3);
  const int e   = wg / (NX * NYT);
  const int rem = wg - e * (NX * NYT);
  const int ty  = rem % NYT;           // y fastest: consecutive ids share B-panel (L2)
  const int tx  = rem / NYT;
  const int m0  = ty * 256, n0 = tx * BN;

  // M-tile skip: output rows >= count[e] are never combined (src<0), so skip whole tiles
  const int cnt   = counts[e];
  const int tiles = (cnt + 255) >> 8;
  if (ty >= ((tiles < NYT) ? tiles : NYT)) return;

  const __bf16* Ae = A + (size_t)e * sA;
  const __bf16* Be = B + (size_t)e * sB;
  const int tid = threadIdx.x;
  const int wid = tid >> 6, lane = tid & 63;
  const int wm = wid >> 2, wn = wid & 3;     // 2M x 4N wave grid, per-wave out 128 x WNC
  const int rl = lane & 15, gl = lane >> 4;
  // provably wave-uniform wave id (SGPR) for global_load_lds destinations
  const int wu = __builtin_amdgcn_readfirstlane(tid) >> 6;

  f32x4 acc[8][NF];
#pragma unroll
  for (int m = 0; m < 8; ++m)
#pragma unroll
    for (int n = 0; n < NF; ++n) acc[m][n] = (f32x4){0.f, 0.f, 0.f, 0.f};

  // issue TOT = 4 + 2*HB async16 per thread; LDS base wave-uniform (chunk*1024),
  // per-lane swizzle folded into the GLOBAL source address (m173 pattern)
  auto stage = [&](int c, int kt) {
    const int k0 = kt * 64;
#pragma unroll
    for (int h = 0; h < 2; ++h)
#pragma unroll
      for (int i = 0; i < 2; ++i) {
        const int chunk = i * 8 + wu;               // 0..15 (uniform per wave)
        const int s = chunk * 64 + lane;            // 16B slot id 0..1023
        const int row = s >> 3, cg = (s & 7) ^ (row & 7);
        async16(Ae + (size_t)(m0 + h * 128 + row) * K + k0 + cg * 8,
                ldsA + (c * 2 + h) * 16384 + chunk * 1024);
      }
#pragma unroll
    for (int h = 0; h < HB; ++h)
#pragma unroll
      for (int i = 0; i < 2; ++i) {
        const int chunk = i * 8 + wu;
        const int s = chunk * 64 + lane;
        const int row = s >> 3, cg = (s & 7) ^ (row & 7);
        async16(Be + (size_t)(n0 + h * 128 + row) * K + k0 + cg * 8,
                ldsB + (c * HB + h) * 16384 + chunk * 1024);
      }
  };

  auto phase = [&](int c, int kk) {     // 8+NF ds_read_b128 -> 8*NF MFMA
    bf16x8 af[8], bv[NF];
#pragma unroll
    for (int m = 0; m < 8; ++m) {
      const int rowin = m * 16 + rl;
      af[m] = *(const bf16x8*)(ldsA + (c * 2 + wm) * 16384 + rowin * 128 +
                               (((kk * 4 + gl) ^ (rowin & 7)) * 16));
    }
#pragma unroll
    for (int n = 0; n < NF; ++n) {
      const int rowB = wn * WNC + n * 16 + rl;
      const int h = rowB >> 7, rowin = rowB & 127;
      bv[n] = *(const bf16x8*)(ldsB + (c * HB + h) * 16384 + rowin * 128 +
                               (((kk * 4 + gl) ^ (rowin & 7)) * 16));
    }
    __builtin_amdgcn_s_setprio(1);
#pragma unroll
    for (int m = 0; m < 8; ++m)
#pragma unroll
      for (int n = 0; n < NF; ++n)
        acc[m][n] = __builtin_amdgcn_mfma_f32_16x16x32_bf16(af[m], bv[n], acc[m][n], 0, 0, 0);
    __builtin_amdgcn_s_setprio(0);
  };

#define WAIT_TOT() do { if constexpr (HB == 2) \
      asm volatile("s_waitcnt vmcnt(8)" ::: "memory"); \
    else asm volatile("s_waitcnt vmcnt(6)" ::: "memory"); } while (0)

  const int nkt = K >> 6;               // 16 (GEMM1) / 64 (GEMM2) K-tiles, always >= 2
  stage(0, 0);
  stage(1, 1);
  WAIT_TOT();                           // tile 0 landed; tile 1 stays in flight
  asm volatile("" ::: "memory");
  __builtin_amdgcn_s_barrier();
  asm volatile("" ::: "memory");

  for (int t = 0; t < nkt; ++t) {
    const int c = t & 1;
    phase(c, 0);
    phase(c, 1);
    if (t + 1 < nkt) {
      asm volatile("" ::: "memory");
      __builtin_amdgcn_s_barrier();     // B1: all waves done reading buf c
      asm volatile("" ::: "memory");
      if (t + 2 < nkt) {
        stage(c, t + 2);                // overwrite dead buf c with tile t+2
        WAIT_TOT();                     // tile t+1 retired in every wave (t+2 in flight)
      } else {
        asm volatile("s_waitcnt vmcnt(0)" ::: "memory");
      }
      asm volatile("" ::: "memory");
      __builtin_amdgcn_s_barrier();     // B2: buf c^1 (tile t+1) visible to all
      asm volatile("" ::: "memory");
    }
  }
#undef WAIT_TOT

  // C/D layout: col = lane&15, row = (lane>>4)*4 + reg  [m89/m91 verified]
  if (MODE == 0) {
    __bf16* Ce = Cbf + (size_t)e * sC;
#pragma unroll
    for (int m = 0; m < 8; ++m)
#pragma unroll
      for (int j = 0; j < 4; ++j) {
        const int row = m0 + wm * 128 + m * 16 + gl * 4 + j;
#pragma unroll
        for (int n = 0; n < NF; ++n) {
          const int col = n0 + wn * WNC + n * 16 + rl;
          float v = acc[m][n][j];
          v = v > 0.f ? v : 0.f;        // fused ReLU
          Ce[(size_t)row * N + col] = (__bf16)v;
        }
      }
  } else {
#pragma unroll
    for (int m = 0; m < 8; ++m)
#pragma unroll
      for (int j = 0; j < 4; ++j) {
        const int slot = m0 + wm * 128 + m * 16 + gl * 4 + j;
        const int t = src[e * CAPACITY + slot];
        if (t >= 0) {
          const float p = prob[t];
          float* op = out + (size_t)t * N;
#pragma unroll
          for (int n = 0; n < NF; ++n) {
            const int col = n0 + wn * WNC + n * 16 + rl;
            op[col] = p * acc[m][n][j]; // fused combine (scale + scatter)
          }
        }
      }
  }
}

extern "C" void kernel_launch(void* const* d_in, const int* in_sizes, int n_in,
                              void* d_out, int out_size, void* d_ws, size_t ws_size,
                              hipStream_t stream) {
  const float* x  = (const float*)d_in[0];
  const float* gw = (const float*)d_in[1];
  const float* w1 = (const float*)d_in[2];
  const float* w2 = (const float*)d_in[3];
  float* out = (float*)d_out;

  char* ws = (char*)d_ws;
  size_t off = 0;
  auto alloc = [&](size_t bytes) {
    void* p = ws + off;
    off += (bytes + 255) & ~(size_t)255;
    return p;
  };
  __bf16* W1bT = (__bf16*)alloc((size_t)NEXP * FDIM * DDIM * 2);   // [E][F][D] bf16
  __bf16* W2bT = (__bf16*)alloc((size_t)NEXP * DDIM * FDIM * 2);   // [E][D][F] bf16
  __bf16* Xb   = (__bf16*)alloc((size_t)NEXP * CAPACITY * DDIM * 2);
  __bf16* Hb   = (__bf16*)alloc((size_t)NEXP * CAPACITY * FDIM * 2);
  int*   eidx  = (int*)alloc(TOKENS * sizeof(int));
  float* prob  = (float*)alloc(TOKENS * sizeof(float));
  int*   srcm  = (int*)alloc(NEXP * CAPACITY * sizeof(int));
  int*   cnts  = (int*)alloc(NEXP * sizeof(int));
  (void)ws_size; (void)in_sizes; (void)n_in;

  hipMemsetAsync(d_out, 0, (size_t)out_size * sizeof(float), stream);  // dropped tokens -> 0

  gate_kernel<<<TOKENS, 64, 0, stream>>>(x, gw, eidx, prob);
  scan_kernel<<<1, 256, 0, stream>>>(eidx, srcm, cnts);
  dispatch_kernel<<<NEXP * CAPACITY, 256, 0, stream>>>(x, srcm, Xb);
  transpose_convert_kernel<<<dim3(FDIM / 64, DDIM / 64, NEXP), dim3(64, 4), 0, stream>>>(
      w1, W1bT, DDIM, FDIM);
  transpose_convert_kernel<<<dim3(DDIM / 64, FDIM / 64, NEXP), dim3(64, 4), 0, stream>>>(
      w2, W2bT, FDIM, DDIM);
  // H = relu(Xb @ W1^T): 256x256 tiles, grid = 16*5*8
  gemm8_kernel<256, 0><<<(FDIM / 256) * NYT * NEXP, 512, 0, stream>>>(
      Xb, W1bT, Hb, nullptr, nullptr, nullptr, cnts,
      DDIM, (size_t)CAPACITY * DDIM, (size_t)FDIM * DDIM, (size_t)CAPACITY * FDIM);
  // out[t] = prob[t] * (H @ W2^T)[slot]: 256x128 tiles, grid = 8*5*8
  gemm8_kernel<128, 1><<<(DDIM / 128) * NYT * NEXP, 512, 0, stream>>>(
      Hb, W2bT, nullptr, out, srcm, prob, cnts,
      FDIM, (size_t)CAPACITY * FDIM, (size_t)DDIM * FDIM, 0);
}

// Round 5
// 366.854 us; speedup vs baseline: 1.0513x; 1.0361x over previous
//
#include <hip/hip_runtime.h>
#include <hip/hip_bf16.h>

// Problem constants (B=4, S=2048, D=1024, E=8, F=4096)
#define TOKENS   8192
#define DDIM     1024
#define NEXP     8
#define FDIM     4096
#define CAPACITY 1280
#define NYT      10         // CAPACITY / 128 M-tiles

typedef __attribute__((ext_vector_type(8))) __bf16 bf16x8;
typedef __attribute__((ext_vector_type(4))) __bf16 bf16x4;
typedef __attribute__((ext_vector_type(4))) float  f32x4;

typedef __attribute__((address_space(1))) const void gvoid_t;
typedef __attribute__((address_space(3))) void       lvoid_t;

__device__ __forceinline__ void async16(const void* g, void* l) {
  // 16B per lane; LDS dest = wave-uniform base + lane*16 (HW behavior)
  __builtin_amdgcn_global_load_lds((gvoid_t*)g, (lvoid_t*)l, 16, 0, 0);
}

// ---------------- gating: logits, softmax, top-1 (all f32, must match ref routing) --------
__global__ void gate_kernel(const float* __restrict__ x, const float* __restrict__ gw,
                            int* __restrict__ eidx, float* __restrict__ prob) {
  const int t = blockIdx.x;
  const int lane = threadIdx.x;           // 64 threads
  const float* xp = x + (size_t)t * DDIM;
  float acc[NEXP];
#pragma unroll
  for (int e = 0; e < NEXP; ++e) acc[e] = 0.f;
#pragma unroll 4
  for (int i = 0; i < DDIM / 64; ++i) {
    const int d = i * 64 + lane;
    const float xv = xp[d];
    const f32x4 g0 = *(const f32x4*)(gw + d * NEXP);
    const f32x4 g1 = *(const f32x4*)(gw + d * NEXP + 4);
    acc[0] += xv * g0[0]; acc[1] += xv * g0[1];
    acc[2] += xv * g0[2]; acc[3] += xv * g0[3];
    acc[4] += xv * g1[0]; acc[5] += xv * g1[1];
    acc[6] += xv * g1[2]; acc[7] += xv * g1[3];
  }
#pragma unroll
  for (int e = 0; e < NEXP; ++e) {
    float v = acc[e];
#pragma unroll
    for (int off = 32; off; off >>= 1) v += __shfl_xor(v, off);
    acc[e] = v;
  }
  if (lane == 0) {
    float m = acc[0]; int mi = 0;
#pragma unroll
    for (int e = 1; e < NEXP; ++e) if (acc[e] > m) { m = acc[e]; mi = e; }  // first-occurrence argmax
    float s = 0.f;
#pragma unroll
    for (int e = 0; e < NEXP; ++e) s += __expf(acc[e] - m);
    eidx[t] = mi;
    prob[t] = 1.f / s;       // softmax prob of the argmax expert
  }
}

// ---------------- deterministic per-expert cumsum positions + slot->token map + counts ----
__global__ void scan_kernel(const int* __restrict__ eidx, int* __restrict__ src,
                            int* __restrict__ counts) {
  __shared__ int buf[2][NEXP][256];
  const int tid = threadIdx.x;            // 256 threads, 1 block
  for (int i = tid; i < NEXP * CAPACITY; i += 256) src[i] = -1;
  const int t0 = tid * (TOKENS / 256);    // 32 tokens per thread
#pragma unroll
  for (int e = 0; e < NEXP; ++e) buf[0][e][tid] = 0;
  for (int k = 0; k < TOKENS / 256; ++k) {
    const int e = eidx[t0 + k];
    buf[0][e][tid]++;                     // LDS histogram
  }
  __syncthreads();
  int cur = 0;
  for (int off = 1; off < 256; off <<= 1) {   // Hillis-Steele inclusive scan over threads
#pragma unroll
    for (int e = 0; e < NEXP; ++e) {
      int v = buf[cur][e][tid];
      if (tid >= off) v += buf[cur][e][tid - off];
      buf[cur ^ 1][e][tid] = v;
    }
    __syncthreads();
    cur ^= 1;
  }
  if (tid < NEXP) counts[tid] = buf[cur][tid][255];   // per-expert totals (for M-tile skip)
  // exclusive base -> running counters in the other buffer (own slot only, no race)
#pragma unroll
  for (int e = 0; e < NEXP; ++e)
    buf[cur ^ 1][e][tid] = (tid > 0) ? buf[cur][e][tid - 1] : 0;
  for (int k = 0; k < TOKENS / 256; ++k) {
    const int t = t0 + k;
    const int e = eidx[t];
    const int p = buf[cur ^ 1][e][tid]++;
    if (p < CAPACITY) src[e * CAPACITY + p] = t;   // p>=CAP => token dropped
  }
}

// ---------------- dispatch: scatter tokens (f32 -> bf16) into [E*CAP, D]; zero empty slots
__global__ void dispatch_kernel(const float* __restrict__ tokens, const int* __restrict__ src,
                                __bf16* __restrict__ Xb) {
  const int slot = blockIdx.x;            // E*CAP blocks
  const int tid  = threadIdx.x;           // 256 threads, 4 elems each
  const int t = src[slot];
  bf16x4* dst = (bf16x4*)(Xb + (size_t)slot * DDIM);
  bf16x4 o;
  if (t >= 0) {
    const f32x4 v = ((const f32x4*)(tokens + (size_t)t * DDIM))[tid];
    o[0] = (__bf16)v[0]; o[1] = (__bf16)v[1]; o[2] = (__bf16)v[2]; o[3] = (__bf16)v[3];
  } else {
    o[0] = (__bf16)0.f; o[1] = (__bf16)0.f; o[2] = (__bf16)0.f; o[3] = (__bf16)0.f;
  }
  dst[tid] = o;
}

// ---------------- weight convert f32->bf16 with transpose: w[e][R][C] -> wt[e][C][R] ------
__global__ void transpose_convert_kernel(const float* __restrict__ w, __bf16* __restrict__ wt,
                                         int R, int C) {
  __shared__ __bf16 tile[64][65];         // +1 pad: conflict-free transpose
  const int e = blockIdx.z;
  const float* wp = w + (size_t)e * R * C;
  __bf16* op = wt + (size_t)e * R * C;
  const int c0 = blockIdx.x * 64, r0 = blockIdx.y * 64;
  const int tx = threadIdx.x, ty = threadIdx.y;   // (64,4)
#pragma unroll
  for (int i = 0; i < 16; ++i) {
    const int r = ty + i * 4;
    tile[r][tx] = (__bf16)wp[(size_t)(r0 + r) * C + c0 + tx];
  }
  __syncthreads();
#pragma unroll
  for (int i = 0; i < 16; ++i) {
    const int cc = ty + i * 4;
    op[(size_t)(c0 + cc) * R + r0 + tx] = tile[tx][cc];
  }
}

// ---------------- grouped GEMM, 128x128 tile, BK=64, 4 waves, T3-minimum 2-phase ----------
// C[e] = A[e][M=CAP,K] @ B[e][N,K]^T.  MODE 0: relu->bf16 into Cbf (N=FDIM).
// MODE 1: scatter f32 out[t] = prob[t]*val via src (N=DDIM).
// Per K-tile t: stage(buf^1 <- tile t+1) FIRST (loads fly under compute) ->
// 2 MFMA phases reading buf cur -> __syncthreads (vmcnt(0)+lgkmcnt(0)+barrier,
// once per tile). Double-buffered LDS 64KB -> 2 blocks/CU; inter-block overlap
// (m114) hides the per-tile drain. LDS XOR-swizzle via pre-swizzled global
// source + swizzled ds_read (0 bank conflicts, verified round 1).
template <int MODE>
__global__ __launch_bounds__(256, 2)
void gemm_kernel(const __bf16* __restrict__ A, const __bf16* __restrict__ B,
                 __bf16* __restrict__ Cbf, float* __restrict__ out,
                 const int* __restrict__ src, const float* __restrict__ prob,
                 const int* __restrict__ counts,
                 int K, size_t sA, size_t sB, size_t sC) {
  constexpr int N  = (MODE == 0) ? FDIM : DDIM;
  constexpr int NX = N / 128;
  __shared__ char lds[2][32768];          // [buf][A 16KB | B 16KB], tiles [128][64] bf16

  // bijective XCD swizzle (nwg % 8 == 0 for both instantiations)
  const int nwg = NX * NYT * NEXP;
  int wg = blockIdx.x;
  wg = (wg & 7) * (nwg >> 3) + (wg >> 3);
  const int e   = wg / (NX * NYT);
  const int rem = wg - e * (NX * NYT);
  const int ty  = rem % NYT;              // y fastest: consecutive ids share B-panel (L2)
  const int tx  = rem / NYT;
  const int m0  = ty * 128, n0 = tx * 128;

  // M-tile skip: output rows >= count[e] are never combined (src<0); whole-block uniform
  const int cnt   = counts[e];
  const int tiles = (cnt + 127) >> 7;
  if (ty >= ((tiles < NYT) ? tiles : NYT)) return;

  const __bf16* Ae = A + (size_t)e * sA;
  const __bf16* Be = B + (size_t)e * sB;
  const int tid = threadIdx.x;
  const int wid = tid >> 6, lane = tid & 63;
  const int wm = wid >> 1, wn = wid & 1;  // 2x2 wave grid, per-wave out 64x64
  const int rl = lane & 15, gl = lane >> 4;
  const int wu = __builtin_amdgcn_readfirstlane(tid) >> 6;  // wave id in SGPR

  f32x4 acc[4][4];
#pragma unroll
  for (int m = 0; m < 4; ++m)
#pragma unroll
    for (int n = 0; n < 4; ++n) acc[m][n] = (f32x4){0.f, 0.f, 0.f, 0.f};

  // 4 A-loads + 4 B-loads per thread; LDS dest wave-uniform chunk, per-lane
  // XOR swizzle folded into the GLOBAL source address (m173 pattern)
  auto stage = [&](int c, int kt) {
    const int k0 = kt * 64;
#pragma unroll
    for (int i = 0; i < 4; ++i) {
      const int chunk = i * 4 + wu;       // 0..15, uniform per wave
      const int s = chunk * 64 + lane;    // 16B slot id 0..1023
      const int row = s >> 3, cg = (s & 7) ^ (row & 7);
      async16(Ae + (size_t)(m0 + row) * K + k0 + cg * 8, &lds[c][chunk * 1024]);
      async16(Be + (size_t)(n0 + row) * K + k0 + cg * 8, &lds[c][16384 + chunk * 1024]);
    }
  };

  auto phase = [&](int c, int kk) {       // 8 ds_read_b128 -> 16 MFMA
    bf16x8 af[4], bv[4];
#pragma unroll
    for (int m = 0; m < 4; ++m) {
      const int rowin = wm * 64 + m * 16 + rl;
      af[m] = *(const bf16x8*)(&lds[c][rowin * 128 + (((kk * 4 + gl) ^ (rowin & 7)) * 16)]);
    }
#pragma unroll
    for (int n = 0; n < 4; ++n) {
      const int rowin = wn * 64 + n * 16 + rl;
      bv[n] = *(const bf16x8*)(&lds[c][16384 + rowin * 128 +
                                       (((kk * 4 + gl) ^ (rowin & 7)) * 16)]);
    }
    __builtin_amdgcn_s_setprio(1);
#pragma unroll
    for (int m = 0; m < 4; ++m)
#pragma unroll
      for (int n = 0; n < 4; ++n)
        acc[m][n] = __builtin_amdgcn_mfma_f32_16x16x32_bf16(af[m], bv[n], acc[m][n], 0, 0, 0);
    __builtin_amdgcn_s_setprio(0);
  };

  const int nkt = K >> 6;                 // 16 (GEMM1) / 64 (GEMM2)
  stage(0, 0);
  __syncthreads();                        // prologue drain (vmcnt(0) + barrier)
  for (int t = 0; t < nkt; ++t) {
    const int cur = t & 1;
    if (t + 1 < nkt) stage(cur ^ 1, t + 1);   // issue next tile BEFORE compute (T3)
    phase(cur, 0);
    phase(cur, 1);
    if (t + 1 < nkt) __syncthreads();     // one vmcnt(0)+barrier per K-tile
  }

  // C/D layout: col = lane&15, row = (lane>>4)*4 + reg  [m89/m91 verified]
  if (MODE == 0) {
    __bf16* Ce = Cbf + (size_t)e * sC;
#pragma unroll
    for (int m = 0; m < 4; ++m)
#pragma unroll
      for (int j = 0; j < 4; ++j) {
        const int row = m0 + wm * 64 + m * 16 + gl * 4 + j;
#pragma unroll
        for (int n = 0; n < 4; ++n) {
          const int col = n0 + wn * 64 + n * 16 + rl;
          float v = acc[m][n][j];
          v = v > 0.f ? v : 0.f;          // fused ReLU
          Ce[(size_t)row * N + col] = (__bf16)v;
        }
      }
  } else {
#pragma unroll
    for (int m = 0; m < 4; ++m)
#pragma unroll
      for (int j = 0; j < 4; ++j) {
        const int slot = m0 + wm * 64 + m * 16 + gl * 4 + j;
        const int t = src[e * CAPACITY + slot];
        if (t >= 0) {
          const float p = prob[t];
          float* op = out + (size_t)t * N;
#pragma unroll
          for (int n = 0; n < 4; ++n) {
            const int col = n0 + wn * 64 + n * 16 + rl;
            op[col] = p * acc[m][n][j];   // fused combine (scale + scatter)
          }
        }
      }
  }
}

extern "C" void kernel_launch(void* const* d_in, const int* in_sizes, int n_in,
                              void* d_out, int out_size, void* d_ws, size_t ws_size,
                              hipStream_t stream) {
  const float* x  = (const float*)d_in[0];
  const float* gw = (const float*)d_in[1];
  const float* w1 = (const float*)d_in[2];
  const float* w2 = (const float*)d_in[3];
  float* out = (float*)d_out;

  char* ws = (char*)d_ws;
  size_t off = 0;
  auto alloc = [&](size_t bytes) {
    void* p = ws + off;
    off += (bytes + 255) & ~(size_t)255;
    return p;
  };
  __bf16* W1bT = (__bf16*)alloc((size_t)NEXP * FDIM * DDIM * 2);   // [E][F][D] bf16
  __bf16* W2bT = (__bf16*)alloc((size_t)NEXP * DDIM * FDIM * 2);   // [E][D][F] bf16
  __bf16* Xb   = (__bf16*)alloc((size_t)NEXP * CAPACITY * DDIM * 2);
  __bf16* Hb   = (__bf16*)alloc((size_t)NEXP * CAPACITY * FDIM * 2);
  int*   eidx  = (int*)alloc(TOKENS * sizeof(int));
  float* prob  = (float*)alloc(TOKENS * sizeof(float));
  int*   srcm  = (int*)alloc(NEXP * CAPACITY * sizeof(int));
  int*   cnts  = (int*)alloc(NEXP * sizeof(int));
  (void)ws_size; (void)in_sizes; (void)n_in;

  hipMemsetAsync(d_out, 0, (size_t)out_size * sizeof(float), stream);  // dropped tokens -> 0

  gate_kernel<<<TOKENS, 64, 0, stream>>>(x, gw, eidx, prob);
  scan_kernel<<<1, 256, 0, stream>>>(eidx, srcm, cnts);
  dispatch_kernel<<<NEXP * CAPACITY, 256, 0, stream>>>(x, srcm, Xb);
  transpose_convert_kernel<<<dim3(FDIM / 64, DDIM / 64, NEXP), dim3(64, 4), 0, stream>>>(
      w1, W1bT, DDIM, FDIM);
  transpose_convert_kernel<<<dim3(DDIM / 64, FDIM / 64, NEXP), dim3(64, 4), 0, stream>>>(
      w2, W2bT, FDIM, DDIM);
  // H = relu(Xb @ W1^T): grid = 32*10*8 = 2560
  gemm_kernel<0><<<(FDIM / 128) * NYT * NEXP, 256, 0, stream>>>(
      Xb, W1bT, Hb, nullptr, nullptr, nullptr, cnts,
      DDIM, (size_t)CAPACITY * DDIM, (size_t)FDIM * DDIM, (size_t)CAPACITY * FDIM);
  // out[t] = prob[t] * (H @ W2^T)[slot]: grid = 8*10*8 = 640
  gemm_kernel<1><<<(DDIM / 128) * NYT * NEXP, 256, 0, stream>>>(
      Hb, W2bT, nullptr, out, srcm, prob, cnts,
      FDIM, (size_t)CAPACITY * FDIM, (size_t)DDIM * FDIM, 0);
}

// Round 6
// 326.458 us; speedup vs baseline: 1.1814x; 1.1237x over previous
//
#include <hip/hip_runtime.h>
#include <hip/hip_bf16.h>

// Problem constants (B=4, S=2048, D=1024, E=8, F=4096)
#define TOKENS   8192
#define DDIM     1024
#define NEXP     8
#define FDIM     4096
#define CAPACITY 1280
#define NYT      10         // CAPACITY / 128 M-tiles

typedef __attribute__((ext_vector_type(8))) __bf16 bf16x8;
typedef __attribute__((ext_vector_type(4))) __bf16 bf16x4;
typedef __attribute__((ext_vector_type(4))) float  f32x4;

typedef __attribute__((address_space(1))) const void gvoid_t;
typedef __attribute__((address_space(3))) void       lvoid_t;

__device__ __forceinline__ void async16(const void* g, void* l) {
  // 16B per lane; LDS dest = wave-uniform base + lane*16 (HW behavior)
  __builtin_amdgcn_global_load_lds((gvoid_t*)g, (lvoid_t*)l, 16, 0, 0);
}

// ---------------- gating: logits, softmax, top-1 (all f32, must match ref routing) --------
__global__ void gate_kernel(const float* __restrict__ x, const float* __restrict__ gw,
                            int* __restrict__ eidx, float* __restrict__ prob) {
  const int t = blockIdx.x;
  const int lane = threadIdx.x;           // 64 threads
  const float* xp = x + (size_t)t * DDIM;
  float acc[NEXP];
#pragma unroll
  for (int e = 0; e < NEXP; ++e) acc[e] = 0.f;
#pragma unroll 4
  for (int i = 0; i < DDIM / 64; ++i) {
    const int d = i * 64 + lane;
    const float xv = xp[d];
    const f32x4 g0 = *(const f32x4*)(gw + d * NEXP);
    const f32x4 g1 = *(const f32x4*)(gw + d * NEXP + 4);
    acc[0] += xv * g0[0]; acc[1] += xv * g0[1];
    acc[2] += xv * g0[2]; acc[3] += xv * g0[3];
    acc[4] += xv * g1[0]; acc[5] += xv * g1[1];
    acc[6] += xv * g1[2]; acc[7] += xv * g1[3];
  }
#pragma unroll
  for (int e = 0; e < NEXP; ++e) {
    float v = acc[e];
#pragma unroll
    for (int off = 32; off; off >>= 1) v += __shfl_xor(v, off);
    acc[e] = v;
  }
  if (lane == 0) {
    float m = acc[0]; int mi = 0;
#pragma unroll
    for (int e = 1; e < NEXP; ++e) if (acc[e] > m) { m = acc[e]; mi = e; }  // first-occurrence argmax
    float s = 0.f;
#pragma unroll
    for (int e = 0; e < NEXP; ++e) s += __expf(acc[e] - m);
    eidx[t] = mi;
    prob[t] = 1.f / s;       // softmax prob of the argmax expert
  }
}

// ---------------- deterministic per-expert cumsum positions + slot->token map + counts ----
__global__ void scan_kernel(const int* __restrict__ eidx, int* __restrict__ src,
                            int* __restrict__ counts) {
  __shared__ int buf[2][NEXP][256];
  const int tid = threadIdx.x;            // 256 threads, 1 block
  for (int i = tid; i < NEXP * CAPACITY; i += 256) src[i] = -1;
  const int t0 = tid * (TOKENS / 256);    // 32 tokens per thread
#pragma unroll
  for (int e = 0; e < NEXP; ++e) buf[0][e][tid] = 0;
  for (int k = 0; k < TOKENS / 256; ++k) {
    const int e = eidx[t0 + k];
    buf[0][e][tid]++;                     // LDS histogram
  }
  __syncthreads();
  int cur = 0;
  for (int off = 1; off < 256; off <<= 1) {   // Hillis-Steele inclusive scan over threads
#pragma unroll
    for (int e = 0; e < NEXP; ++e) {
      int v = buf[cur][e][tid];
      if (tid >= off) v += buf[cur][e][tid - off];
      buf[cur ^ 1][e][tid] = v;
    }
    __syncthreads();
    cur ^= 1;
  }
  if (tid < NEXP) counts[tid] = buf[cur][tid][255];   // per-expert totals (for M-tile skip)
  // exclusive base -> running counters in the other buffer (own slot only, no race)
#pragma unroll
  for (int e = 0; e < NEXP; ++e)
    buf[cur ^ 1][e][tid] = (tid > 0) ? buf[cur][e][tid - 1] : 0;
  for (int k = 0; k < TOKENS / 256; ++k) {
    const int t = t0 + k;
    const int e = eidx[t];
    const int p = buf[cur ^ 1][e][tid]++;
    if (p < CAPACITY) src[e * CAPACITY + p] = t;   // p>=CAP => token dropped
  }
}

// ---------------- dispatch: scatter tokens (f32 -> bf16) into [E*CAP, D]; zero empty slots
__global__ void dispatch_kernel(const float* __restrict__ tokens, const int* __restrict__ src,
                                __bf16* __restrict__ Xb) {
  const int slot = blockIdx.x;            // E*CAP blocks
  const int tid  = threadIdx.x;           // 256 threads, 4 elems each
  const int t = src[slot];
  bf16x4* dst = (bf16x4*)(Xb + (size_t)slot * DDIM);
  bf16x4 o;
  if (t >= 0) {
    const f32x4 v = ((const f32x4*)(tokens + (size_t)t * DDIM))[tid];
    o[0] = (__bf16)v[0]; o[1] = (__bf16)v[1]; o[2] = (__bf16)v[2]; o[3] = (__bf16)v[3];
  } else {
    o[0] = (__bf16)0.f; o[1] = (__bf16)0.f; o[2] = (__bf16)0.f; o[3] = (__bf16)0.f;
  }
  dst[tid] = o;
}

// ---------------- weight convert f32->bf16 with transpose: w[e][R][C] -> wt[e][C][R] ------
// Vectorized both sides (G13): f32x4 global reads, bf16x8 global writes; 64x64 LDS tile.
__global__ void transpose_convert_kernel(const float* __restrict__ w, __bf16* __restrict__ wt,
                                         int R, int C) {
  __shared__ __bf16 tile[64][66];         // pad 2: 8-row stride = 264 dwords % 32 != 0
  const int e = blockIdx.z;
  const float* wp = w + (size_t)e * R * C;
  __bf16* op = wt + (size_t)e * R * C;
  const int c0 = blockIdx.x * 64, r0 = blockIdx.y * 64;
  const int tid = threadIdx.x;            // 256 threads
#pragma unroll
  for (int p = 0; p < 4; ++p) {           // load 16 rows/pass, f32x4 per thread
    const int r = p * 16 + (tid >> 4);
    const int c = (tid & 15) * 4;
    const f32x4 v = *(const f32x4*)(wp + (size_t)(r0 + r) * C + c0 + c);
    tile[r][c]     = (__bf16)v[0]; tile[r][c + 1] = (__bf16)v[1];
    tile[r][c + 2] = (__bf16)v[2]; tile[r][c + 3] = (__bf16)v[3];
  }
  __syncthreads();
#pragma unroll
  for (int p = 0; p < 2; ++p) {           // store 32 out-rows/pass, bf16x8 per thread
    const int c  = p * 32 + (tid >> 3);   // output row (original column)
    const int rg = (tid & 7) * 8;         // 8 consecutive original rows
    bf16x8 o;
#pragma unroll
    for (int i = 0; i < 8; ++i) o[i] = tile[rg + i][c];
    *(bf16x8*)(op + (size_t)(c0 + c) * R + r0 + rg) = o;
  }
}

// ---------------- grouped GEMM, 128x128 tile, BK=64, 4 waves, round-1 schedule ------------
// C[e] = A[e][M=CAP,K] @ B[e][N,K]^T.  MODE 0: relu->bf16 into Cbf (N=FDIM).
// MODE 1: scatter f32 out[t] = prob[t]*val via src (N=DDIM).
// Schedule = round-1's proven stage -> sync -> 2 MFMA phases -> sync (single 32KB
// LDS buffer, ~5 blocks/CU; inter-block overlap per m114 hides the drain — every
// pipelined variant R3-R5 measured SLOWER). Kept from R5: bijective XCD swizzle,
// y-fastest ordering (FETCH 369->85MB), 128-row M-tile skip (-20% FLOPs).
// LDS XOR-swizzle via pre-swizzled global source + swizzled ds_read (0 conflicts).
template <int MODE>
__global__ __launch_bounds__(256, 2)
void gemm_kernel(const __bf16* __restrict__ A, const __bf16* __restrict__ B,
                 __bf16* __restrict__ Cbf, float* __restrict__ out,
                 const int* __restrict__ src, const float* __restrict__ prob,
                 const int* __restrict__ counts,
                 int K, size_t sA, size_t sB, size_t sC) {
  constexpr int N  = (MODE == 0) ? FDIM : DDIM;
  constexpr int NX = N / 128;
  __shared__ __bf16 lds[2][128 * 64];     // [0]=A tile [128][64], [1]=B tile (32 KB total)

  // bijective XCD swizzle (nwg % 8 == 0 for both instantiations)
  const int nwg = NX * NYT * NEXP;
  int wg = blockIdx.x;
  wg = (wg & 7) * (nwg >> 3) + (wg >> 3);
  const int e   = wg / (NX * NYT);
  const int rem = wg - e * (NX * NYT);
  const int ty  = rem % NYT;              // y fastest: consecutive ids share B-panel (L2)
  const int tx  = rem / NYT;
  const int m0  = ty * 128, n0 = tx * 128;

  // M-tile skip: output rows >= count[e] are never combined (src<0); whole-block uniform
  const int cnt   = counts[e];
  const int tiles = (cnt + 127) >> 7;
  if (ty >= ((tiles < NYT) ? tiles : NYT)) return;

  const __bf16* Ae = A + (size_t)e * sA;
  const __bf16* Be = B + (size_t)e * sB;
  const int tid = threadIdx.x;
  const int wid = tid >> 6, lane = tid & 63;
  const int wm = wid >> 1, wn = wid & 1;  // 2x2 wave grid, per-wave out 64x64
  const int rl = lane & 15, gl = lane >> 4;

  f32x4 acc[4][4];
#pragma unroll
  for (int m = 0; m < 4; ++m)
#pragma unroll
    for (int n = 0; n < 4; ++n) acc[m][n] = (f32x4){0.f, 0.f, 0.f, 0.f};

  for (int kt = 0; kt < K; kt += 64) {
    // stage 16KB A + 16KB B; LDS dest wave-uniform chunk, per-lane XOR swizzle
    // folded into the GLOBAL source address (m173 pattern)
#pragma unroll
    for (int i = 0; i < 4; ++i) {
      const int s   = (wid * 4 + i) * 64 + lane;    // 16B slot id
      const int row = s >> 3;                       // tile row (8 granules/row)
      const int cg  = (s & 7) ^ (row & 7);          // swizzled source granule
      async16(Ae + (size_t)(m0 + row) * K + kt + cg * 8, &lds[0][(wid * 4 + i) * 512]);
      async16(Be + (size_t)(n0 + row) * K + kt + cg * 8, &lds[1][(wid * 4 + i) * 512]);
    }
    __syncthreads();                                // drains vmcnt before barrier
    const char* la = (const char*)&lds[0][0];
    const char* lb = (const char*)&lds[1][0];
#pragma unroll
    for (int kk = 0; kk < 2; ++kk) {
      bf16x8 af[4], bv[4];
#pragma unroll
      for (int m = 0; m < 4; ++m) {
        const int rowin = wm * 64 + m * 16 + rl;
        af[m] = *(const bf16x8*)(la + rowin * 128 + (((kk * 4 + gl) ^ (rowin & 7)) * 16));
      }
#pragma unroll
      for (int n = 0; n < 4; ++n) {
        const int rowin = wn * 64 + n * 16 + rl;
        bv[n] = *(const bf16x8*)(lb + rowin * 128 + (((kk * 4 + gl) ^ (rowin & 7)) * 16));
      }
#pragma unroll
      for (int m = 0; m < 4; ++m)
#pragma unroll
        for (int n = 0; n < 4; ++n)
          acc[m][n] = __builtin_amdgcn_mfma_f32_16x16x32_bf16(af[m], bv[n], acc[m][n], 0, 0, 0);
    }
    __syncthreads();
  }

  // C/D layout: col = lane&15, row = (lane>>4)*4 + reg  [m89/m91 verified]
  if (MODE == 0) {
    __bf16* Ce = Cbf + (size_t)e * sC;
#pragma unroll
    for (int m = 0; m < 4; ++m)
#pragma unroll
      for (int j = 0; j < 4; ++j) {
        const int row = m0 + wm * 64 + m * 16 + gl * 4 + j;
#pragma unroll
        for (int n = 0; n < 4; ++n) {
          const int col = n0 + wn * 64 + n * 16 + rl;
          float v = acc[m][n][j];
          v = v > 0.f ? v : 0.f;          // fused ReLU
          Ce[(size_t)row * N + col] = (__bf16)v;
        }
      }
  } else {
#pragma unroll
    for (int m = 0; m < 4; ++m)
#pragma unroll
      for (int j = 0; j < 4; ++j) {
        const int slot = m0 + wm * 64 + m * 16 + gl * 4 + j;
        const int t = src[e * CAPACITY + slot];
        if (t >= 0) {
          const float p = prob[t];
          float* op = out + (size_t)t * N;
#pragma unroll
          for (int n = 0; n < 4; ++n) {
            const int col = n0 + wn * 64 + n * 16 + rl;
            op[col] = p * acc[m][n][j];   // fused combine (scale + scatter)
          }
        }
      }
  }
}

extern "C" void kernel_launch(void* const* d_in, const int* in_sizes, int n_in,
                              void* d_out, int out_size, void* d_ws, size_t ws_size,
                              hipStream_t stream) {
  const float* x  = (const float*)d_in[0];
  const float* gw = (const float*)d_in[1];
  const float* w1 = (const float*)d_in[2];
  const float* w2 = (const float*)d_in[3];
  float* out = (float*)d_out;

  char* ws = (char*)d_ws;
  size_t off = 0;
  auto alloc = [&](size_t bytes) {
    void* p = ws + off;
    off += (bytes + 255) & ~(size_t)255;
    return p;
  };
  __bf16* W1bT = (__bf16*)alloc((size_t)NEXP * FDIM * DDIM * 2);   // [E][F][D] bf16
  __bf16* W2bT = (__bf16*)alloc((size_t)NEXP * DDIM * FDIM * 2);   // [E][D][F] bf16
  __bf16* Xb   = (__bf16*)alloc((size_t)NEXP * CAPACITY * DDIM * 2);
  __bf16* Hb   = (__bf16*)alloc((size_t)NEXP * CAPACITY * FDIM * 2);
  int*   eidx  = (int*)alloc(TOKENS * sizeof(int));
  float* prob  = (float*)alloc(TOKENS * sizeof(float));
  int*   srcm  = (int*)alloc(NEXP * CAPACITY * sizeof(int));
  int*   cnts  = (int*)alloc(NEXP * sizeof(int));
  (void)ws_size; (void)in_sizes; (void)n_in;

  hipMemsetAsync(d_out, 0, (size_t)out_size * sizeof(float), stream);  // dropped tokens -> 0

  gate_kernel<<<TOKENS, 64, 0, stream>>>(x, gw, eidx, prob);
  scan_kernel<<<1, 256, 0, stream>>>(eidx, srcm, cnts);
  dispatch_kernel<<<NEXP * CAPACITY, 256, 0, stream>>>(x, srcm, Xb);
  transpose_convert_kernel<<<dim3(FDIM / 64, DDIM / 64, NEXP), 256, 0, stream>>>(
      w1, W1bT, DDIM, FDIM);
  transpose_convert_kernel<<<dim3(DDIM / 64, FDIM / 64, NEXP), 256, 0, stream>>>(
      w2, W2bT, FDIM, DDIM);
  // H = relu(Xb @ W1^T): grid = 32*10*8 = 2560
  gemm_kernel<0><<<(FDIM / 128) * NYT * NEXP, 256, 0, stream>>>(
      Xb, W1bT, Hb, nullptr, nullptr, nullptr, cnts,
      DDIM, (size_t)CAPACITY * DDIM, (size_t)FDIM * DDIM, (size_t)CAPACITY * FDIM);
  // out[t] = prob[t] * (H @ W2^T)[slot]: grid = 8*10*8 = 640
  gemm_kernel<1><<<(DDIM / 128) * NYT * NEXP, 256, 0, stream>>>(
      Hb, W2bT, nullptr, out, srcm, prob, cnts,
      FDIM, (size_t)CAPACITY * FDIM, (size_t)DDIM * FDIM, 0);
}